// Round 14
// baseline (614.951 us; speedup 1.0000x reference)
//
#include <hip/hip_runtime.h>
#include <hip/hip_bf16.h>
#include <stdint.h>

// LoRA int8-dequant linear, MI355X/gfx950 — int8 main path, square wave tiles.
//   Xi8[8192][4096] = rne(x * 127/absmax_row),  tstep[m] = absmax_row/127
//   Wi8[4096][4096] = qweight codes (exact i8)
//   out = (Xi8 @ Wi8^T)_i32 * (tstep[m]*scale[o]) + xa @ (2B)^T
// Main GEMM: 256x256 block tile, BK=64, 4 waves x (128x128) wave tiles
// (square tile halves LDS-read bytes per MFMA op: 64 KB vs 96 KB per tile),
// mfma_i32_16x16x64_i8, 4-deep LDS (128 KB), full frag prefetch one tile
// ahead, counted vmcnt(8), 1 barrier/K-tile.

typedef __bf16 bf16x8 __attribute__((ext_vector_type(8)));
typedef float f32x4 __attribute__((ext_vector_type(4)));
typedef int i32x4 __attribute__((ext_vector_type(4)));

#define DIN   4096
#define DOUT  4096
#define MTOT  8192
#define RNK   64
#define NT    64

__device__ inline void gload_lds16(const void* g, void* l) {
  __builtin_amdgcn_global_load_lds((const __attribute__((address_space(1))) void*)g,
                                   (__attribute__((address_space(3))) void*)l,
                                   16, 0, 0);
}

// ==== merged prep: blocks [0,8192) quant x rows; [8192,8256) quant lora_A
// rows; [8256,8512) Blt = bf16(2*lora_B); [8512,24896) Wi8 = i8(qweight) ====
__global__ __launch_bounds__(256) void prep_kernel(const float* __restrict__ x,
                                                   const int* __restrict__ qw,
                                                   const float* __restrict__ lA,
                                                   const float* __restrict__ lB,
                                                   signed char* __restrict__ Xi8,
                                                   float* __restrict__ tstep,
                                                   signed char* __restrict__ Wi8,
                                                   signed char* __restrict__ Ai8,
                                                   float* __restrict__ astep,
                                                   __bf16* __restrict__ Blt) {
  const int bid = blockIdx.x, t = threadIdx.x;
  const float* src = nullptr;
  signed char* dst = nullptr;
  float* stp = nullptr;
  int row = 0;
  if (bid < 8192) { src = x; dst = Xi8; stp = tstep; row = bid; }
  else if (bid < 8256) { src = lA; dst = Ai8; stp = astep; row = bid - 8192; }
  if (src) {
    const float4* xr = (const float4*)(src + (size_t)row * DIN);
    float4 v[4];
    float m = 0.f;
#pragma unroll
    for (int s = 0; s < 4; ++s) {
      v[s] = xr[t + s * 256];
      m = fmaxf(m, fmaxf(fmaxf(fabsf(v[s].x), fabsf(v[s].y)),
                         fmaxf(fabsf(v[s].z), fabsf(v[s].w))));
    }
#pragma unroll
    for (int off = 32; off > 0; off >>= 1) m = fmaxf(m, __shfl_xor(m, off));
    __shared__ float wm[4];
    if ((t & 63) == 0) wm[t >> 6] = m;
    __syncthreads();
    m = fmaxf(fmaxf(wm[0], wm[1]), fmaxf(wm[2], wm[3]));
    m = fmaxf(m, 1e-30f);
    const float rs = 127.0f / m;
    int* orow = (int*)(dst + (size_t)row * DIN);
#pragma unroll
    for (int s = 0; s < 4; ++s) {
      float e[4] = {v[s].x, v[s].y, v[s].z, v[s].w};
      union { signed char c[4]; int i; } p;
#pragma unroll
      for (int j = 0; j < 4; ++j) {
        int q = __float2int_rn(e[j] * rs);
        q = q > 127 ? 127 : (q < -127 ? -127 : q);
        p.c[j] = (signed char)q;
      }
      orow[t + s * 256] = p.i;
    }
    if (t == 0) stp[row] = m * (1.0f / 127.0f);
  } else if (bid < 8512) {
    int i = (bid - 8256) * 256 + t;
    float4 v = ((const float4*)lB)[i];
    union { __bf16 h[4]; uint64_t u; } p;
    p.h[0] = (__bf16)(2.0f * v.x); p.h[1] = (__bf16)(2.0f * v.y);
    p.h[2] = (__bf16)(2.0f * v.z); p.h[3] = (__bf16)(2.0f * v.w);
    ((uint64_t*)Blt)[i] = p.u;
  } else {
    int i = (bid - 8512) * 256 + t;
    int4 v = ((const int4*)qw)[i];
    union { signed char c[4]; int i; } p;
    p.c[0] = (signed char)v.x; p.c[1] = (signed char)v.y;
    p.c[2] = (signed char)v.z; p.c[3] = (signed char)v.w;
    ((int*)Wi8)[i] = p.i;
  }
}

// ---- xa = (Xi8 @ Ai8^T)*tstep*astep -> bf16 [8192][64] ----
__global__ __launch_bounds__(256) void lora_xa_kernel(const signed char* __restrict__ Xi8,
                                                      const float* __restrict__ tstep,
                                                      const signed char* __restrict__ Ai8,
                                                      const float* __restrict__ astep,
                                                      __bf16* __restrict__ xa) {
  __shared__ i32x4 red[4][64][4];
  const int w = threadIdx.x >> 6, lane = threadIdx.x & 63;
  const int rowbase = blockIdx.x * 16;
  i32x4 acc[4] = {};
  const int k00 = w * 1024 + (lane >> 4) * 16;
  const signed char* xrow = Xi8 + (size_t)(rowbase + (lane & 15)) * DIN + k00;
  const signed char* ab = Ai8 + (size_t)(lane & 15) * DIN + k00;
#pragma unroll 4
  for (int k = 0; k < 1024; k += 64) {
    i32x4 af = *(const i32x4*)(xrow + k);
#pragma unroll
    for (int ni = 0; ni < 4; ++ni) {
      i32x4 bv = *(const i32x4*)(ab + (size_t)ni * 16 * DIN + k);
      acc[ni] = __builtin_amdgcn_mfma_i32_16x16x64_i8(af, bv, acc[ni], 0, 0, 0);
    }
  }
#pragma unroll
  for (int ni = 0; ni < 4; ++ni) red[w][lane][ni] = acc[ni];
  __syncthreads();
  if (w == 0) {
    f32x4 tm = *(const f32x4*)&tstep[rowbase + (lane >> 4) * 4];
#pragma unroll
    for (int ni = 0; ni < 4; ++ni) {
      i32x4 s = red[0][lane][ni];
#pragma unroll
      for (int u = 1; u < 4; ++u) s += red[u][lane][ni];
      const int col = ni * 16 + (lane & 15);
      const float as = astep[col];
#pragma unroll
      for (int j = 0; j < 4; ++j) {
        int row = rowbase + (lane >> 4) * 4 + j;
        xa[(size_t)row * RNK + col] = (__bf16)((float)s[j] * tm[j] * as);
      }
    }
  }
}

// ==== i8 main GEMM: 256x256 block, 4 waves x (128x128), 4-deep LDS ====
// LDS 128 KB: 4 bufs x 32 KB, buf = { A 256x64 i8 @0, B 256x64 i8 @16K }.
// Row r, 16B-slot s at phys slot s ^ ((r>>1)&3) (proven conflict-free).
// Body(kt): stage(kt+3)->buf[(kt+3)&3] (8 gloads); prefetch kt+1's 16 frags
// from buf[(kt+1)&3] (landed: vmcnt(8) at end of body kt-1, published by its
// barrier); 64 MFMA on kt's reg-resident frags; vmcnt(8); barrier.
// stage target buf[(kt+3)&3] == buf[(kt-1)&3]: its last ds_reads were the
// prefetch in body kt-2, two barriers prior — safe.
__global__ __launch_bounds__(256, 1) void gemm_i8_kernel(const signed char* __restrict__ Xi8,
                                                         const signed char* __restrict__ Wi8,
                                                         const float* __restrict__ scale,
                                                         const float* __restrict__ tstep,
                                                         const __bf16* __restrict__ xa,
                                                         const __bf16* __restrict__ Blt,
                                                         float* __restrict__ out) {
  extern __shared__ char smem[];
  const int tid = threadIdx.x;
  const int lane = tid & 63;
  const int w = tid >> 6;        // wave 0..3
  const int wr = w >> 1;         // 0..1 -> rows wr*128
  const int wc = w & 1;          // 0..1 -> cols wc*128

  const int swz = (blockIdx.x & 7) * 64 + (blockIdx.x >> 3);  // bijective XCD swizzle
  const int bx = swz & 15;
  const int by = swz >> 4;
  const size_t bm = (size_t)by * 256, bn = (size_t)bx * 256;

  const int rc = ((lane >> 4) ^ ((lane >> 1) & 3)) << 4;
  const int srow = tid >> 2;                              // 0..63
  const int scol = ((tid & 3) ^ ((tid >> 3) & 3)) << 4;   // inverse-swz src col

  auto stage = [&](int srct, int buf) {
    int b = buf * 32768;
#pragma unroll
    for (int i = 0; i < 4; ++i)
      gload_lds16(Xi8 + (bm + 64 * i + srow) * (size_t)4096 + srct * 64 + scol,
                  smem + b + i * 4096 + tid * 16);
#pragma unroll
    for (int i = 0; i < 4; ++i)
      gload_lds16(Wi8 + (bn + 64 * i + srow) * (size_t)4096 + srct * 64 + scol,
                  smem + b + 16384 + i * 4096 + tid * 16);
  };

  const int aoff = wr * 8192 + (lane & 15) * 64 + rc;
  const int boff = 16384 + wc * 8192 + (lane & 15) * 64 + rc;

  i32x4 aP[8], bP[8], aQ[8], bQ[8];
  i32x4 acc[8][8] = {};

  // prologue: tiles 0,1,2 staged; vmcnt(8) -> 0,1 landed; preload tile0 frags
  stage(0, 0); stage(1, 1); stage(2, 2);
  asm volatile("s_waitcnt vmcnt(8)" ::: "memory");
  __builtin_amdgcn_s_barrier();
#pragma unroll
  for (int mi = 0; mi < 8; ++mi) aP[mi] = *(const i32x4*)(smem + aoff + mi * 1024);
#pragma unroll
  for (int ni = 0; ni < 8; ++ni) bP[ni] = *(const i32x4*)(smem + boff + ni * 1024);

  auto body = [&](int kt, i32x4 (&aC)[8], i32x4 (&bC)[8],
                  i32x4 (&aN)[8], i32x4 (&bN)[8]) {
    const int st = (kt + 3 < NT) ? kt + 3 : NT - 1;   // clamped dummy keeps vmcnt uniform
    stage(st, (kt + 3) & 3);
    if (kt + 1 < NT) {
      const int nb = ((kt + 1) & 3) * 32768;
#pragma unroll
      for (int mi = 0; mi < 8; ++mi) aN[mi] = *(const i32x4*)(smem + nb + aoff + mi * 1024);
#pragma unroll
      for (int ni = 0; ni < 8; ++ni) bN[ni] = *(const i32x4*)(smem + nb + boff + ni * 1024);
    }
#pragma unroll
    for (int mi = 0; mi < 8; ++mi)
#pragma unroll
      for (int ni = 0; ni < 8; ++ni)
        acc[mi][ni] = __builtin_amdgcn_mfma_i32_16x16x64_i8(aC[mi], bC[ni], acc[mi][ni], 0, 0, 0);
    __builtin_amdgcn_sched_barrier(0);
    asm volatile("s_waitcnt vmcnt(8)" ::: "memory");
    __builtin_amdgcn_s_barrier();
  };

  for (int kt = 0; kt < NT; kt += 2) {
    body(kt, aP, bP, aQ, bQ);
    body(kt + 1, aQ, bQ, aP, bP);
  }

  // ---- epilogue: drain dummies, stage xa (32 KB @0) / Blt (32 KB @32K),
  // bf16 rows of 128B, phys slot = logical ^ (row&7) ----
  asm volatile("s_waitcnt vmcnt(0)" ::: "memory");
  __builtin_amdgcn_s_barrier();
  const int erow = tid >> 3;                               // 0..31 rows/instr
  const int ecol = (((tid & 7) ^ ((tid >> 3) & 7)) << 4);  // inverse-swz src col
#pragma unroll
  for (int i = 0; i < 8; ++i)
    gload_lds16((const char*)xa + (bm + 32 * i + erow) * 128 + ecol,
                smem + i * 4096 + tid * 16);
#pragma unroll
  for (int i = 0; i < 8; ++i)
    gload_lds16((const char*)Blt + (bn + 32 * i + erow) * 128 + ecol,
                smem + 32768 + i * 4096 + tid * 16);

  float sc[8];
#pragma unroll
  for (int ni = 0; ni < 8; ++ni)
    sc[ni] = scale[bn + wc * 128 + ni * 16 + (lane & 15)];
  f32x4 tm[8];
#pragma unroll
  for (int mi = 0; mi < 8; ++mi)
    tm[mi] = *(const f32x4*)&tstep[bm + wr * 128 + mi * 16 + (lane >> 4) * 4];

  asm volatile("s_waitcnt vmcnt(0)" ::: "memory");
  __builtin_amdgcn_s_barrier();

  const int cx0 = ((lane >> 4) << 4) ^ ((lane & 7) << 4);
  const int cx1 = (64 | ((lane >> 4) << 4)) ^ ((lane & 7) << 4);
  const int abE = wr * 16384 + (lane & 15) * 128;
  const int bbE = 32768 + wc * 16384 + (lane & 15) * 128;

#pragma unroll
  for (int mi = 0; mi < 8; ++mi) {
    bf16x8 ax0 = *(const bf16x8*)(smem + abE + mi * 2048 + cx0);
    bf16x8 ax1 = *(const bf16x8*)(smem + abE + mi * 2048 + cx1);
    const size_t row = bm + wr * 128 + mi * 16 + (lane >> 4) * 4;
#pragma unroll
    for (int ni = 0; ni < 8; ++ni) {
      bf16x8 bl0 = *(const bf16x8*)(smem + bbE + ni * 2048 + cx0);
      bf16x8 bl1 = *(const bf16x8*)(smem + bbE + ni * 2048 + cx1);
      f32x4 l = {0.f, 0.f, 0.f, 0.f};
      l = __builtin_amdgcn_mfma_f32_16x16x32_bf16(ax0, bl0, l, 0, 0, 0);
      l = __builtin_amdgcn_mfma_f32_16x16x32_bf16(ax1, bl1, l, 0, 0, 0);
      const size_t col = bn + wc * 128 + ni * 16 + (lane & 15);
#pragma unroll
      for (int j = 0; j < 4; ++j)
        out[(row + j) * DOUT + col] = (float)acc[mi][ni][j] * (sc[ni] * tm[mi][j]) + l[j];
    }
  }
}

extern "C" void kernel_launch(void* const* d_in, const int* in_sizes, int n_in,
                              void* d_out, int out_size, void* d_ws, size_t ws_size,
                              hipStream_t stream) {
  const float* x = (const float*)d_in[0];
  const int* qw = (const int*)d_in[1];
  const float* scale = (const float*)d_in[2];
  const float* lA = (const float*)d_in[3];
  const float* lB = (const float*)d_in[4];
  float* out = (float*)d_out;

  char* ws = (char*)d_ws;
  signed char* Xi8 = (signed char*)ws;                              // 33.6 MB
  signed char* Wi8 = (signed char*)(ws + 33554432);                 // 16.8 MB
  __bf16* xa    = (__bf16*)(ws + 50331648);                         // 1.05 MB
  signed char* Ai8 = (signed char*)(ws + 51380224);                 // 0.26 MB
  __bf16* Blt   = (__bf16*)(ws + 51904512);                         // 0.52 MB
  float* tstep  = (float*)(ws + 52428800);                          // 32 KB
  float* astep  = (float*)(ws + 52461568);                          // 256 B

  hipFuncSetAttribute((const void*)gemm_i8_kernel,
                      hipFuncAttributeMaxDynamicSharedMemorySize, 131072);

  prep_kernel<<<24896, 256, 0, stream>>>(x, qw, lA, lB, Xi8, tstep, Wi8, Ai8, astep, Blt);
  lora_xa_kernel<<<MTOT / 16, 256, 0, stream>>>(Xi8, tstep, Ai8, astep, xa);
  gemm_i8_kernel<<<(MTOT / 256) * (DOUT / 256), 256, 131072, stream>>>(
      Xi8, Wi8, scale, tstep, xa, Blt, out);
}

// Round 15
// 357.449 us; speedup vs baseline: 1.7204x; 1.7204x over previous
//
#include <hip/hip_runtime.h>
#include <hip/hip_bf16.h>
#include <stdint.h>

// LoRA int8-dequant linear, MI355X/gfx950 — int8, square wave tiles, AGPR acc.
//   Xi8[8192][4096] = rne(x * 127/absmax_row),  tstep[m] = absmax_row/127
//   Wi8[4096][4096] = qweight codes (exact i8)
//   out = (Xi8 @ Wi8^T)_i32 * (tstep[m]*scale[o]) + xa @ (2B)^T
// Main GEMM: 256x256 block tile, BK=64, 4 waves x (128x128) wave tiles,
// mfma_i32_16x16x64_i8 with accumulator FORCED into AGPRs via inline-asm
// "+a" constraint (R14 spilled because the compiler kept 256 acc regs in
// VGPRs). 4-deep LDS (128 KB), full frag prefetch one tile ahead, counted
// vmcnt(8), 1 barrier/K-tile. LDS reads 64 KB/tile < MFMA shadow.

typedef __bf16 bf16x8 __attribute__((ext_vector_type(8)));
typedef float f32x4 __attribute__((ext_vector_type(4)));
typedef int i32x4 __attribute__((ext_vector_type(4)));

#define DIN   4096
#define DOUT  4096
#define MTOT  8192
#define RNK   64
#define NT    64

#define MFMA_I8_A(acc_, a_, b_) \
  asm volatile("v_mfma_i32_16x16x64_i8 %0, %1, %2, %0" : "+a"(acc_) : "v"(a_), "v"(b_))

__device__ inline void gload_lds16(const void* g, void* l) {
  __builtin_amdgcn_global_load_lds((const __attribute__((address_space(1))) void*)g,
                                   (__attribute__((address_space(3))) void*)l,
                                   16, 0, 0);
}

// ==== merged prep: blocks [0,8192) quant x rows; [8192,8256) quant lora_A
// rows; [8256,8512) Blt = bf16(2*lora_B); [8512,24896) Wi8 = i8(qweight) ====
__global__ __launch_bounds__(256) void prep_kernel(const float* __restrict__ x,
                                                   const int* __restrict__ qw,
                                                   const float* __restrict__ lA,
                                                   const float* __restrict__ lB,
                                                   signed char* __restrict__ Xi8,
                                                   float* __restrict__ tstep,
                                                   signed char* __restrict__ Wi8,
                                                   signed char* __restrict__ Ai8,
                                                   float* __restrict__ astep,
                                                   __bf16* __restrict__ Blt) {
  const int bid = blockIdx.x, t = threadIdx.x;
  const float* src = nullptr;
  signed char* dst = nullptr;
  float* stp = nullptr;
  int row = 0;
  if (bid < 8192) { src = x; dst = Xi8; stp = tstep; row = bid; }
  else if (bid < 8256) { src = lA; dst = Ai8; stp = astep; row = bid - 8192; }
  if (src) {
    const float4* xr = (const float4*)(src + (size_t)row * DIN);
    float4 v[4];
    float m = 0.f;
#pragma unroll
    for (int s = 0; s < 4; ++s) {
      v[s] = xr[t + s * 256];
      m = fmaxf(m, fmaxf(fmaxf(fabsf(v[s].x), fabsf(v[s].y)),
                         fmaxf(fabsf(v[s].z), fabsf(v[s].w))));
    }
#pragma unroll
    for (int off = 32; off > 0; off >>= 1) m = fmaxf(m, __shfl_xor(m, off));
    __shared__ float wm[4];
    if ((t & 63) == 0) wm[t >> 6] = m;
    __syncthreads();
    m = fmaxf(fmaxf(wm[0], wm[1]), fmaxf(wm[2], wm[3]));
    m = fmaxf(m, 1e-30f);
    const float rs = 127.0f / m;
    int* orow = (int*)(dst + (size_t)row * DIN);
#pragma unroll
    for (int s = 0; s < 4; ++s) {
      float e[4] = {v[s].x, v[s].y, v[s].z, v[s].w};
      union { signed char c[4]; int i; } p;
#pragma unroll
      for (int j = 0; j < 4; ++j) {
        int q = __float2int_rn(e[j] * rs);
        q = q > 127 ? 127 : (q < -127 ? -127 : q);
        p.c[j] = (signed char)q;
      }
      orow[t + s * 256] = p.i;
    }
    if (t == 0) stp[row] = m * (1.0f / 127.0f);
  } else if (bid < 8512) {
    int i = (bid - 8256) * 256 + t;
    float4 v = ((const float4*)lB)[i];
    union { __bf16 h[4]; uint64_t u; } p;
    p.h[0] = (__bf16)(2.0f * v.x); p.h[1] = (__bf16)(2.0f * v.y);
    p.h[2] = (__bf16)(2.0f * v.z); p.h[3] = (__bf16)(2.0f * v.w);
    ((uint64_t*)Blt)[i] = p.u;
  } else {
    int i = (bid - 8512) * 256 + t;
    int4 v = ((const int4*)qw)[i];
    union { signed char c[4]; int i; } p;
    p.c[0] = (signed char)v.x; p.c[1] = (signed char)v.y;
    p.c[2] = (signed char)v.z; p.c[3] = (signed char)v.w;
    ((int*)Wi8)[i] = p.i;
  }
}

// ---- xa = (Xi8 @ Ai8^T)*tstep*astep -> bf16 [8192][64] ----
__global__ __launch_bounds__(256) void lora_xa_kernel(const signed char* __restrict__ Xi8,
                                                      const float* __restrict__ tstep,
                                                      const signed char* __restrict__ Ai8,
                                                      const float* __restrict__ astep,
                                                      __bf16* __restrict__ xa) {
  __shared__ i32x4 red[4][64][4];
  const int w = threadIdx.x >> 6, lane = threadIdx.x & 63;
  const int rowbase = blockIdx.x * 16;
  i32x4 acc[4] = {};
  const int k00 = w * 1024 + (lane >> 4) * 16;
  const signed char* xrow = Xi8 + (size_t)(rowbase + (lane & 15)) * DIN + k00;
  const signed char* ab = Ai8 + (size_t)(lane & 15) * DIN + k00;
#pragma unroll 4
  for (int k = 0; k < 1024; k += 64) {
    i32x4 af = *(const i32x4*)(xrow + k);
#pragma unroll
    for (int ni = 0; ni < 4; ++ni) {
      i32x4 bv = *(const i32x4*)(ab + (size_t)ni * 16 * DIN + k);
      acc[ni] = __builtin_amdgcn_mfma_i32_16x16x64_i8(af, bv, acc[ni], 0, 0, 0);
    }
  }
#pragma unroll
  for (int ni = 0; ni < 4; ++ni) red[w][lane][ni] = acc[ni];
  __syncthreads();
  if (w == 0) {
    f32x4 tm = *(const f32x4*)&tstep[rowbase + (lane >> 4) * 4];
#pragma unroll
    for (int ni = 0; ni < 4; ++ni) {
      i32x4 s = red[0][lane][ni];
#pragma unroll
      for (int u = 1; u < 4; ++u) s += red[u][lane][ni];
      const int col = ni * 16 + (lane & 15);
      const float as = astep[col];
#pragma unroll
      for (int j = 0; j < 4; ++j) {
        int row = rowbase + (lane >> 4) * 4 + j;
        xa[(size_t)row * RNK + col] = (__bf16)((float)s[j] * tm[j] * as);
      }
    }
  }
}

// ==== i8 main GEMM: 256x256 block, 4 waves x (128x128), AGPR acc ====
// LDS 128 KB: 4 bufs x 32 KB, buf = { A 256x64 i8 @0, B 256x64 i8 @16K }.
// Row r, 16B-slot s at phys slot s ^ ((r>>1)&3) (proven conflict-free).
// Body(kt): stage(kt+3)->buf[(kt+3)&3] (8 gloads); prefetch kt+1's 16 frags
// (buffer landed by end-of-body-kt-1 vmcnt(8) + barrier); 64 AGPR-MFMAs on
// kt's reg-resident frags; vmcnt(8); barrier. stage target == buf[(kt-1)&3],
// last ds-read in body kt-2, two barriers prior — safe.
__global__ __launch_bounds__(256, 1) void gemm_i8_kernel(const signed char* __restrict__ Xi8,
                                                         const signed char* __restrict__ Wi8,
                                                         const float* __restrict__ scale,
                                                         const float* __restrict__ tstep,
                                                         const __bf16* __restrict__ xa,
                                                         const __bf16* __restrict__ Blt,
                                                         float* __restrict__ out) {
  extern __shared__ char smem[];
  const int tid = threadIdx.x;
  const int lane = tid & 63;
  const int w = tid >> 6;        // wave 0..3
  const int wr = w >> 1;         // 0..1 -> rows wr*128
  const int wc = w & 1;          // 0..1 -> cols wc*128

  const int swz = (blockIdx.x & 7) * 64 + (blockIdx.x >> 3);  // bijective XCD swizzle
  const int bx = swz & 15;
  const int by = swz >> 4;
  const size_t bm = (size_t)by * 256, bn = (size_t)bx * 256;

  const int rc = ((lane >> 4) ^ ((lane >> 1) & 3)) << 4;
  const int srow = tid >> 2;                              // 0..63
  const int scol = ((tid & 3) ^ ((tid >> 3) & 3)) << 4;   // inverse-swz src col

  auto stage = [&](int srct, int buf) {
    int b = buf * 32768;
#pragma unroll
    for (int i = 0; i < 4; ++i)
      gload_lds16(Xi8 + (bm + 64 * i + srow) * (size_t)4096 + srct * 64 + scol,
                  smem + b + i * 4096 + tid * 16);
#pragma unroll
    for (int i = 0; i < 4; ++i)
      gload_lds16(Wi8 + (bn + 64 * i + srow) * (size_t)4096 + srct * 64 + scol,
                  smem + b + 16384 + i * 4096 + tid * 16);
  };

  const int aoff = wr * 8192 + (lane & 15) * 64 + rc;
  const int boff = 16384 + wc * 8192 + (lane & 15) * 64 + rc;

  i32x4 aP[8], bP[8], aQ[8], bQ[8];
  i32x4 acc[8][8] = {};   // forced to AGPRs by the "+a" asm constraint

  // prologue: tiles 0,1,2 staged; vmcnt(8) -> 0,1 landed; preload tile0 frags
  stage(0, 0); stage(1, 1); stage(2, 2);
  asm volatile("s_waitcnt vmcnt(8)" ::: "memory");
  __builtin_amdgcn_s_barrier();
#pragma unroll
  for (int mi = 0; mi < 8; ++mi) aP[mi] = *(const i32x4*)(smem + aoff + mi * 1024);
#pragma unroll
  for (int ni = 0; ni < 8; ++ni) bP[ni] = *(const i32x4*)(smem + boff + ni * 1024);

  auto body = [&](int kt, i32x4 (&aC)[8], i32x4 (&bC)[8],
                  i32x4 (&aN)[8], i32x4 (&bN)[8]) {
    const int st = (kt + 3 < NT) ? kt + 3 : NT - 1;   // clamped dummy keeps vmcnt uniform
    stage(st, (kt + 3) & 3);
    if (kt + 1 < NT) {
      const int nb = ((kt + 1) & 3) * 32768;
#pragma unroll
      for (int mi = 0; mi < 8; ++mi) aN[mi] = *(const i32x4*)(smem + nb + aoff + mi * 1024);
#pragma unroll
      for (int ni = 0; ni < 8; ++ni) bN[ni] = *(const i32x4*)(smem + nb + boff + ni * 1024);
    }
#pragma unroll
    for (int mi = 0; mi < 8; ++mi)
#pragma unroll
      for (int ni = 0; ni < 8; ++ni)
        MFMA_I8_A(acc[mi][ni], aC[mi], bC[ni]);
    __builtin_amdgcn_sched_barrier(0);
    asm volatile("s_waitcnt vmcnt(8)" ::: "memory");
    __builtin_amdgcn_s_barrier();
  };

  for (int kt = 0; kt < NT; kt += 2) {
    body(kt, aP, bP, aQ, bQ);
    body(kt + 1, aQ, bQ, aP, bP);
  }

  // ---- epilogue: drain dummies, stage xa (32 KB @0) / Blt (32 KB @32K),
  // bf16 rows of 128B, phys slot = logical ^ (row&7) ----
  asm volatile("s_waitcnt vmcnt(0)" ::: "memory");
  __builtin_amdgcn_s_barrier();
  const int erow = tid >> 3;                               // 0..31 rows/instr
  const int ecol = (((tid & 7) ^ ((tid >> 3) & 7)) << 4);  // inverse-swz src col
#pragma unroll
  for (int i = 0; i < 8; ++i)
    gload_lds16((const char*)xa + (bm + 32 * i + erow) * 128 + ecol,
                smem + i * 4096 + tid * 16);
#pragma unroll
  for (int i = 0; i < 8; ++i)
    gload_lds16((const char*)Blt + (bn + 32 * i + erow) * 128 + ecol,
                smem + 32768 + i * 4096 + tid * 16);

  float sc[8];
#pragma unroll
  for (int ni = 0; ni < 8; ++ni)
    sc[ni] = scale[bn + wc * 128 + ni * 16 + (lane & 15)];
  f32x4 tm[8];
#pragma unroll
  for (int mi = 0; mi < 8; ++mi)
    tm[mi] = *(const f32x4*)&tstep[bm + wr * 128 + mi * 16 + (lane >> 4) * 4];

  asm volatile("s_waitcnt vmcnt(0)" ::: "memory");
  __builtin_amdgcn_s_barrier();

  const int cx0 = ((lane >> 4) << 4) ^ ((lane & 7) << 4);
  const int cx1 = (64 | ((lane >> 4) << 4)) ^ ((lane & 7) << 4);
  const int abE = wr * 16384 + (lane & 15) * 128;
  const int bbE = 32768 + wc * 16384 + (lane & 15) * 128;

#pragma unroll
  for (int mi = 0; mi < 8; ++mi) {
    bf16x8 ax0 = *(const bf16x8*)(smem + abE + mi * 2048 + cx0);
    bf16x8 ax1 = *(const bf16x8*)(smem + abE + mi * 2048 + cx1);
    const size_t row = bm + wr * 128 + mi * 16 + (lane >> 4) * 4;
#pragma unroll
    for (int ni = 0; ni < 8; ++ni) {
      bf16x8 bl0 = *(const bf16x8*)(smem + bbE + ni * 2048 + cx0);
      bf16x8 bl1 = *(const bf16x8*)(smem + bbE + ni * 2048 + cx1);
      f32x4 l = {0.f, 0.f, 0.f, 0.f};
      l = __builtin_amdgcn_mfma_f32_16x16x32_bf16(ax0, bl0, l, 0, 0, 0);
      l = __builtin_amdgcn_mfma_f32_16x16x32_bf16(ax1, bl1, l, 0, 0, 0);
      const size_t col = bn + wc * 128 + ni * 16 + (lane & 15);
      i32x4 av = acc[mi][ni];
#pragma unroll
      for (int j = 0; j < 4; ++j)
        out[(row + j) * DOUT + col] = (float)av[j] * (sc[ni] * tm[mi][j]) + l[j];
    }
  }
}

extern "C" void kernel_launch(void* const* d_in, const int* in_sizes, int n_in,
                              void* d_out, int out_size, void* d_ws, size_t ws_size,
                              hipStream_t stream) {
  const float* x = (const float*)d_in[0];
  const int* qw = (const int*)d_in[1];
  const float* scale = (const float*)d_in[2];
  const float* lA = (const float*)d_in[3];
  const float* lB = (const float*)d_in[4];
  float* out = (float*)d_out;

  char* ws = (char*)d_ws;
  signed char* Xi8 = (signed char*)ws;                              // 33.6 MB
  signed char* Wi8 = (signed char*)(ws + 33554432);                 // 16.8 MB
  __bf16* xa    = (__bf16*)(ws + 50331648);                         // 1.05 MB
  signed char* Ai8 = (signed char*)(ws + 51380224);                 // 0.26 MB
  __bf16* Blt   = (__bf16*)(ws + 51904512);                         // 0.52 MB
  float* tstep  = (float*)(ws + 52428800);                          // 32 KB
  float* astep  = (float*)(ws + 52461568);                          // 256 B

  hipFuncSetAttribute((const void*)gemm_i8_kernel,
                      hipFuncAttributeMaxDynamicSharedMemorySize, 131072);

  prep_kernel<<<24896, 256, 0, stream>>>(x, qw, lA, lB, Xi8, tstep, Wi8, Ai8, astep, Blt);
  lora_xa_kernel<<<MTOT / 16, 256, 0, stream>>>(Xi8, tstep, Ai8, astep, xa);
  gemm_i8_kernel<<<(MTOT / 256) * (DOUT / 256), 256, 131072, stream>>>(
      Xi8, Wi8, scale, tstep, xa, Blt, out);
}

// Round 16
// 199.072 us; speedup vs baseline: 3.0891x; 1.7956x over previous
//
#include <hip/hip_runtime.h>
#include <hip/hip_bf16.h>
#include <stdint.h>

// LoRA int8-dequant linear, MI355X/gfx950 — int8 main path (R10 revert; best
// measured: GEMM 133.5 us, total 198.7 us).
//   Xi8[8192][4096] = rne(x * 127/absmax_row),  tstep[m] = absmax_row/127
//   Wi8[4096][4096] = qweight codes (exact i8)
//   out = (Xi8 @ Wi8^T)_i32 * (tstep[m]*scale[o]) + xa @ (2B)^T
// Main GEMM: 256x256 tile, BK=64, 8 waves, mfma_i32_16x16x64_i8, 4-deep LDS
// (128 KB), pipelined ds_reads, counted vmcnt(4), no setprio (lockstep).

typedef __bf16 bf16x8 __attribute__((ext_vector_type(8)));
typedef float f32x4 __attribute__((ext_vector_type(4)));
typedef int i32x4 __attribute__((ext_vector_type(4)));

#define DIN   4096
#define DOUT  4096
#define MTOT  8192
#define RNK   64
#define NT    64

__device__ inline void gload_lds16(const void* g, void* l) {
  __builtin_amdgcn_global_load_lds((const __attribute__((address_space(1))) void*)g,
                                   (__attribute__((address_space(3))) void*)l,
                                   16, 0, 0);
}

// ==== merged prep: blocks [0,8192) quant x rows; [8192,8256) quant lora_A
// rows; [8256,8512) Blt = bf16(2*lora_B); [8512,24896) Wi8 = i8(qweight) ====
__global__ __launch_bounds__(256) void prep_kernel(const float* __restrict__ x,
                                                   const int* __restrict__ qw,
                                                   const float* __restrict__ lA,
                                                   const float* __restrict__ lB,
                                                   signed char* __restrict__ Xi8,
                                                   float* __restrict__ tstep,
                                                   signed char* __restrict__ Wi8,
                                                   signed char* __restrict__ Ai8,
                                                   float* __restrict__ astep,
                                                   __bf16* __restrict__ Blt) {
  const int bid = blockIdx.x, t = threadIdx.x;
  const float* src = nullptr;
  signed char* dst = nullptr;
  float* stp = nullptr;
  int row = 0;
  if (bid < 8192) { src = x; dst = Xi8; stp = tstep; row = bid; }
  else if (bid < 8256) { src = lA; dst = Ai8; stp = astep; row = bid - 8192; }
  if (src) {
    const float4* xr = (const float4*)(src + (size_t)row * DIN);
    float4 v[4];
    float m = 0.f;
#pragma unroll
    for (int s = 0; s < 4; ++s) {
      v[s] = xr[t + s * 256];
      m = fmaxf(m, fmaxf(fmaxf(fabsf(v[s].x), fabsf(v[s].y)),
                         fmaxf(fabsf(v[s].z), fabsf(v[s].w))));
    }
#pragma unroll
    for (int off = 32; off > 0; off >>= 1) m = fmaxf(m, __shfl_xor(m, off));
    __shared__ float wm[4];
    if ((t & 63) == 0) wm[t >> 6] = m;
    __syncthreads();
    m = fmaxf(fmaxf(wm[0], wm[1]), fmaxf(wm[2], wm[3]));
    m = fmaxf(m, 1e-30f);
    const float rs = 127.0f / m;
    int* orow = (int*)(dst + (size_t)row * DIN);
#pragma unroll
    for (int s = 0; s < 4; ++s) {
      float e[4] = {v[s].x, v[s].y, v[s].z, v[s].w};
      union { signed char c[4]; int i; } p;
#pragma unroll
      for (int j = 0; j < 4; ++j) {
        int q = __float2int_rn(e[j] * rs);
        q = q > 127 ? 127 : (q < -127 ? -127 : q);
        p.c[j] = (signed char)q;
      }
      orow[t + s * 256] = p.i;
    }
    if (t == 0) stp[row] = m * (1.0f / 127.0f);
  } else if (bid < 8512) {
    int i = (bid - 8256) * 256 + t;
    float4 v = ((const float4*)lB)[i];
    union { __bf16 h[4]; uint64_t u; } p;
    p.h[0] = (__bf16)(2.0f * v.x); p.h[1] = (__bf16)(2.0f * v.y);
    p.h[2] = (__bf16)(2.0f * v.z); p.h[3] = (__bf16)(2.0f * v.w);
    ((uint64_t*)Blt)[i] = p.u;
  } else {
    int i = (bid - 8512) * 256 + t;
    int4 v = ((const int4*)qw)[i];
    union { signed char c[4]; int i; } p;
    p.c[0] = (signed char)v.x; p.c[1] = (signed char)v.y;
    p.c[2] = (signed char)v.z; p.c[3] = (signed char)v.w;
    ((int*)Wi8)[i] = p.i;
  }
}

// ---- xa = (Xi8 @ Ai8^T)*tstep*astep -> bf16 [8192][64] ----
// 512 blocks x 4 waves; wave w owns K in [w*1024,(w+1)*1024); exact i32
// LDS reduce across waves; wave 0 scales + writes.
__global__ __launch_bounds__(256) void lora_xa_kernel(const signed char* __restrict__ Xi8,
                                                      const float* __restrict__ tstep,
                                                      const signed char* __restrict__ Ai8,
                                                      const float* __restrict__ astep,
                                                      __bf16* __restrict__ xa) {
  __shared__ i32x4 red[4][64][4];
  const int w = threadIdx.x >> 6, lane = threadIdx.x & 63;
  const int rowbase = blockIdx.x * 16;
  i32x4 acc[4] = {};
  const int k00 = w * 1024 + (lane >> 4) * 16;
  const signed char* xrow = Xi8 + (size_t)(rowbase + (lane & 15)) * DIN + k00;
  const signed char* ab = Ai8 + (size_t)(lane & 15) * DIN + k00;
#pragma unroll 4
  for (int k = 0; k < 1024; k += 64) {
    i32x4 af = *(const i32x4*)(xrow + k);
#pragma unroll
    for (int ni = 0; ni < 4; ++ni) {
      i32x4 bv = *(const i32x4*)(ab + (size_t)ni * 16 * DIN + k);
      acc[ni] = __builtin_amdgcn_mfma_i32_16x16x64_i8(af, bv, acc[ni], 0, 0, 0);
    }
  }
#pragma unroll
  for (int ni = 0; ni < 4; ++ni) red[w][lane][ni] = acc[ni];
  __syncthreads();
  if (w == 0) {
    f32x4 tm = *(const f32x4*)&tstep[rowbase + (lane >> 4) * 4];
#pragma unroll
    for (int ni = 0; ni < 4; ++ni) {
      i32x4 s = red[0][lane][ni];
#pragma unroll
      for (int u = 1; u < 4; ++u) s += red[u][lane][ni];
      const int col = ni * 16 + (lane & 15);
      const float as = astep[col];
#pragma unroll
      for (int j = 0; j < 4; ++j) {
        int row = rowbase + (lane >> 4) * 4 + j;
        xa[(size_t)row * RNK + col] = (__bf16)((float)s[j] * tm[j] * as);
      }
    }
  }
}

// ==== i8 main GEMM, pipelined (R10 structure) ====
// LDS 128 KB: 4 bufs x 32 KB, buf = { A0(8K rows0-127), A1(8K), B0, B1 }.
// Half = 128 rows x 64 i8; row r, 16B-slot s at phys slot s ^ ((r>>1)&3).
// Body(kt): stage(kt+3)->buf[(kt+3)&3]; ds a2(kt); MFMA lo (operands already
// in regs from previous body); ds a/b of buf[(kt+1)&3] -> next-state regs;
// MFMA hi; vmcnt(4); barrier.
__global__ __launch_bounds__(512, 1) void gemm_i8_kernel(const signed char* __restrict__ Xi8,
                                                         const signed char* __restrict__ Wi8,
                                                         const float* __restrict__ scale,
                                                         const float* __restrict__ tstep,
                                                         const __bf16* __restrict__ xa,
                                                         const __bf16* __restrict__ Blt,
                                                         float* __restrict__ out) {
  extern __shared__ char smem[];
  const int tid = threadIdx.x;
  const int lane = tid & 63;
  const int w = tid >> 6;
  const int wr = w >> 2;
  const int wc = w & 3;

  const int swz = (blockIdx.x & 7) * 64 + (blockIdx.x >> 3);
  const int bx = swz & 15;
  const int by = swz >> 4;
  const size_t bm = (size_t)by * 256, bn = (size_t)bx * 256;

  const int rc = ((lane >> 4) ^ ((lane >> 1) & 3)) << 4;
  const int srow = tid >> 2;
  const int scol = ((tid & 3) ^ ((tid >> 3) & 3)) << 4;

  auto SH = [&](const signed char* g, size_t r0, int srct, int ldsoff) {
    gload_lds16(g + (r0 + srow) * (size_t)4096 + srct * 64 + scol,
                smem + ldsoff + tid * 16);
  };
  auto stage = [&](int srct, int buf) {
    int b = buf * 32768;
    SH(Xi8, bm, srct, b); SH(Xi8, bm + 128, srct, b + 8192);
    SH(Wi8, bn, srct, b + 16384); SH(Wi8, bn + 128, srct, b + 24576);
  };

  i32x4 aP[4], bP[4], aQ[4], bQ[4], a2[4];
  i32x4 acc[8][4] = {};

  stage(0, 0); stage(1, 1); stage(2, 2);
  asm volatile("s_waitcnt vmcnt(4)" ::: "memory");
  __builtin_amdgcn_s_barrier();
  {
    const int ab0 = wr * 8192 + (lane & 15) * 64 + rc;
    const int bb0 = 16384 + (wc >> 1) * 8192 + (wc & 1) * 4096 + (lane & 15) * 64 + rc;
#pragma unroll
    for (int mi = 0; mi < 4; ++mi) aP[mi] = *(const i32x4*)(smem + ab0 + mi * 1024);
#pragma unroll
    for (int ni = 0; ni < 4; ++ni) bP[ni] = *(const i32x4*)(smem + bb0 + ni * 1024);
  }

  auto body = [&](int kt, auto& ac, auto& bc, auto& an, auto& bn) {
    const int bufb = (kt & 3) * 32768;
    const int ab = bufb + wr * 8192 + (lane & 15) * 64 + rc;
    const int st = (kt + 3 < NT) ? kt + 3 : NT - 1;
    stage(st, (kt + 3) & 3);
#pragma unroll
    for (int mi = 0; mi < 4; ++mi)
      a2[mi] = *(const i32x4*)(smem + ab + 4096 + mi * 1024);
#pragma unroll
    for (int mi = 0; mi < 4; ++mi)
#pragma unroll
      for (int ni = 0; ni < 4; ++ni)
        acc[mi][ni] = __builtin_amdgcn_mfma_i32_16x16x64_i8(ac[mi], bc[ni], acc[mi][ni], 0, 0, 0);
    const int nbufb = ((kt + 1) & 3) * 32768;
    const int nab = nbufb + wr * 8192 + (lane & 15) * 64 + rc;
    const int nbb = nbufb + 16384 + (wc >> 1) * 8192 + (wc & 1) * 4096 + (lane & 15) * 64 + rc;
#pragma unroll
    for (int mi = 0; mi < 4; ++mi) an[mi] = *(const i32x4*)(smem + nab + mi * 1024);
#pragma unroll
    for (int ni = 0; ni < 4; ++ni) bn[ni] = *(const i32x4*)(smem + nbb + ni * 1024);
#pragma unroll
    for (int mi = 0; mi < 4; ++mi)
#pragma unroll
      for (int ni = 0; ni < 4; ++ni)
        acc[4 + mi][ni] = __builtin_amdgcn_mfma_i32_16x16x64_i8(a2[mi], bc[ni], acc[4 + mi][ni], 0, 0, 0);
    __builtin_amdgcn_sched_barrier(0);
    asm volatile("s_waitcnt vmcnt(4)" ::: "memory");
    __builtin_amdgcn_s_barrier();
  };

  for (int kt = 0; kt < NT; kt += 2) {
    body(kt, aP, bP, aQ, bQ);
    body(kt + 1, aQ, bQ, aP, bP);
  }

  // ---- epilogue: stage xa/Blt (bf16, rows of 128B, phys slot = log ^ (r&7)) ----
  const int sl_row = lane >> 3;
  const int sl_col = ((lane & 7) ^ (lane >> 3)) << 4;
  auto SBF = [&](const __bf16* g, size_t r0, int ldsoff) {
    char* d0 = smem + ldsoff + w * 2048 + lane * 16;
#pragma unroll
    for (int s = 0; s < 2; ++s) {
      const int rl = (w * 2 + s) * 8 + sl_row;
      gload_lds16((const char*)g + (r0 + rl) * 128 + sl_col, d0 + s * 1024);
    }
  };
  SBF(xa, bm, 0); SBF(xa, bm + 128, 16384);
  SBF(Blt, bn, 32768); SBF(Blt, bn + 128, 49152);

  float sc[4];
#pragma unroll
  for (int ni = 0; ni < 4; ++ni)
    sc[ni] = scale[bn + wc * 64 + ni * 16 + (lane & 15)];
  f32x4 tm[8];
#pragma unroll
  for (int mi = 0; mi < 8; ++mi)
    tm[mi] = *(const f32x4*)&tstep[bm + wr * 128 + mi * 16 + (lane >> 4) * 4];

  asm volatile("s_waitcnt vmcnt(0)" ::: "memory");
  __builtin_amdgcn_s_barrier();

  const int cx0 = ((lane >> 4) << 4) ^ ((lane & 7) << 4);
  const int cx1 = (64 | ((lane >> 4) << 4)) ^ ((lane & 7) << 4);
  const int abE = wr * 16384 + (lane & 15) * 128;
  const int bbE = 32768 + (wc >> 1) * 16384 + ((wc & 1) * 64 + (lane & 15)) * 128;

  bf16x8 bl0[4], bl1[4];
#pragma unroll
  for (int ni = 0; ni < 4; ++ni) {
    bl0[ni] = *(const bf16x8*)(smem + bbE + ni * 2048 + cx0);
    bl1[ni] = *(const bf16x8*)(smem + bbE + ni * 2048 + cx1);
  }
#pragma unroll
  for (int mi = 0; mi < 8; ++mi) {
    bf16x8 ax0 = *(const bf16x8*)(smem + abE + mi * 2048 + cx0);
    bf16x8 ax1 = *(const bf16x8*)(smem + abE + mi * 2048 + cx1);
    const size_t row = bm + wr * 128 + mi * 16 + (lane >> 4) * 4;
#pragma unroll
    for (int ni = 0; ni < 4; ++ni) {
      f32x4 l = {0.f, 0.f, 0.f, 0.f};
      l = __builtin_amdgcn_mfma_f32_16x16x32_bf16(ax0, bl0[ni], l, 0, 0, 0);
      l = __builtin_amdgcn_mfma_f32_16x16x32_bf16(ax1, bl1[ni], l, 0, 0, 0);
      const size_t col = bn + wc * 64 + ni * 16 + (lane & 15);
#pragma unroll
      for (int j = 0; j < 4; ++j)
        out[(row + j) * DOUT + col] = (float)acc[mi][ni][j] * (sc[ni] * tm[mi][j]) + l[j];
    }
  }
}

extern "C" void kernel_launch(void* const* d_in, const int* in_sizes, int n_in,
                              void* d_out, int out_size, void* d_ws, size_t ws_size,
                              hipStream_t stream) {
  const float* x = (const float*)d_in[0];
  const int* qw = (const int*)d_in[1];
  const float* scale = (const float*)d_in[2];
  const float* lA = (const float*)d_in[3];
  const float* lB = (const float*)d_in[4];
  float* out = (float*)d_out;

  char* ws = (char*)d_ws;
  signed char* Xi8 = (signed char*)ws;                              // 33.6 MB
  signed char* Wi8 = (signed char*)(ws + 33554432);                 // 16.8 MB
  __bf16* xa    = (__bf16*)(ws + 50331648);                         // 1.05 MB
  signed char* Ai8 = (signed char*)(ws + 51380224);                 // 0.26 MB
  __bf16* Blt   = (__bf16*)(ws + 51904512);                         // 0.52 MB
  float* tstep  = (float*)(ws + 52428800);                          // 32 KB
  float* astep  = (float*)(ws + 52461568);                          // 256 B

  hipFuncSetAttribute((const void*)gemm_i8_kernel,
                      hipFuncAttributeMaxDynamicSharedMemorySize, 131072);

  prep_kernel<<<24896, 256, 0, stream>>>(x, qw, lA, lB, Xi8, tstep, Wi8, Ai8, astep, Blt);
  lora_xa_kernel<<<MTOT / 16, 256, 0, stream>>>(Xi8, tstep, Ai8, astep, xa);
  gemm_i8_kernel<<<(MTOT / 256) * (DOUT / 256), 512, 131072, stream>>>(
      Xi8, Wi8, scale, tstep, xa, Blt, out);
}

// Round 17
// 198.051 us; speedup vs baseline: 3.1050x; 1.0052x over previous
//
#include <hip/hip_runtime.h>
#include <hip/hip_bf16.h>
#include <stdint.h>

// LoRA int8-dequant linear, MI355X/gfx950 — int8, cross-barrier MFMA pipeline.
//   Xi8[8192][4096] = rne(x * 127/absmax_row),  tstep[m] = absmax_row/127
//   Wi8[4096][4096] = qweight codes (exact i8)
//   out = (Xi8 @ Wi8^T)_i32 * (tstep[m]*scale[o]) + xa @ (2B)^T
// Main GEMM: 256x256 tile, BK=64, 8 waves, mfma_i32_16x16x64_i8, 4-deep LDS,
// counted vmcnt(4). R10 base + MFMA-hi cluster pipelined ACROSS the barrier:
// every phase issues 32 register-ready MFMAs, every ds_read gets a full
// phase of latency slack.

typedef __bf16 bf16x8 __attribute__((ext_vector_type(8)));
typedef float f32x4 __attribute__((ext_vector_type(4)));
typedef int i32x4 __attribute__((ext_vector_type(4)));

#define DIN   4096
#define DOUT  4096
#define MTOT  8192
#define RNK   64
#define NT    64

__device__ inline void gload_lds16(const void* g, void* l) {
  __builtin_amdgcn_global_load_lds((const __attribute__((address_space(1))) void*)g,
                                   (__attribute__((address_space(3))) void*)l,
                                   16, 0, 0);
}

// ==== merged prep: blocks [0,8192) quant x rows; [8192,8256) quant lora_A
// rows; [8256,8512) Blt = bf16(2*lora_B); [8512,24896) Wi8 = i8(qweight) ====
__global__ __launch_bounds__(256) void prep_kernel(const float* __restrict__ x,
                                                   const int* __restrict__ qw,
                                                   const float* __restrict__ lA,
                                                   const float* __restrict__ lB,
                                                   signed char* __restrict__ Xi8,
                                                   float* __restrict__ tstep,
                                                   signed char* __restrict__ Wi8,
                                                   signed char* __restrict__ Ai8,
                                                   float* __restrict__ astep,
                                                   __bf16* __restrict__ Blt) {
  const int bid = blockIdx.x, t = threadIdx.x;
  const float* src = nullptr;
  signed char* dst = nullptr;
  float* stp = nullptr;
  int row = 0;
  if (bid < 8192) { src = x; dst = Xi8; stp = tstep; row = bid; }
  else if (bid < 8256) { src = lA; dst = Ai8; stp = astep; row = bid - 8192; }
  if (src) {
    const float4* xr = (const float4*)(src + (size_t)row * DIN);
    float4 v[4];
    float m = 0.f;
#pragma unroll
    for (int s = 0; s < 4; ++s) {
      v[s] = xr[t + s * 256];
      m = fmaxf(m, fmaxf(fmaxf(fabsf(v[s].x), fabsf(v[s].y)),
                         fmaxf(fabsf(v[s].z), fabsf(v[s].w))));
    }
#pragma unroll
    for (int off = 32; off > 0; off >>= 1) m = fmaxf(m, __shfl_xor(m, off));
    __shared__ float wm[4];
    if ((t & 63) == 0) wm[t >> 6] = m;
    __syncthreads();
    m = fmaxf(fmaxf(wm[0], wm[1]), fmaxf(wm[2], wm[3]));
    m = fmaxf(m, 1e-30f);
    const float rs = 127.0f / m;
    int* orow = (int*)(dst + (size_t)row * DIN);
#pragma unroll
    for (int s = 0; s < 4; ++s) {
      float e[4] = {v[s].x, v[s].y, v[s].z, v[s].w};
      union { signed char c[4]; int i; } p;
#pragma unroll
      for (int j = 0; j < 4; ++j) {
        int q = __float2int_rn(e[j] * rs);
        q = q > 127 ? 127 : (q < -127 ? -127 : q);
        p.c[j] = (signed char)q;
      }
      orow[t + s * 256] = p.i;
    }
    if (t == 0) stp[row] = m * (1.0f / 127.0f);
  } else if (bid < 8512) {
    int i = (bid - 8256) * 256 + t;
    float4 v = ((const float4*)lB)[i];
    union { __bf16 h[4]; uint64_t u; } p;
    p.h[0] = (__bf16)(2.0f * v.x); p.h[1] = (__bf16)(2.0f * v.y);
    p.h[2] = (__bf16)(2.0f * v.z); p.h[3] = (__bf16)(2.0f * v.w);
    ((uint64_t*)Blt)[i] = p.u;
  } else {
    int i = (bid - 8512) * 256 + t;
    int4 v = ((const int4*)qw)[i];
    union { signed char c[4]; int i; } p;
    p.c[0] = (signed char)v.x; p.c[1] = (signed char)v.y;
    p.c[2] = (signed char)v.z; p.c[3] = (signed char)v.w;
    ((int*)Wi8)[i] = p.i;
  }
}

// ---- xa = (Xi8 @ Ai8^T)*tstep*astep -> bf16 [8192][64] ----
__global__ __launch_bounds__(256) void lora_xa_kernel(const signed char* __restrict__ Xi8,
                                                      const float* __restrict__ tstep,
                                                      const signed char* __restrict__ Ai8,
                                                      const float* __restrict__ astep,
                                                      __bf16* __restrict__ xa) {
  __shared__ i32x4 red[4][64][4];
  const int w = threadIdx.x >> 6, lane = threadIdx.x & 63;
  const int rowbase = blockIdx.x * 16;
  i32x4 acc[4] = {};
  const int k00 = w * 1024 + (lane >> 4) * 16;
  const signed char* xrow = Xi8 + (size_t)(rowbase + (lane & 15)) * DIN + k00;
  const signed char* ab = Ai8 + (size_t)(lane & 15) * DIN + k00;
#pragma unroll 4
  for (int k = 0; k < 1024; k += 64) {
    i32x4 af = *(const i32x4*)(xrow + k);
#pragma unroll
    for (int ni = 0; ni < 4; ++ni) {
      i32x4 bv = *(const i32x4*)(ab + (size_t)ni * 16 * DIN + k);
      acc[ni] = __builtin_amdgcn_mfma_i32_16x16x64_i8(af, bv, acc[ni], 0, 0, 0);
    }
  }
#pragma unroll
  for (int ni = 0; ni < 4; ++ni) red[w][lane][ni] = acc[ni];
  __syncthreads();
  if (w == 0) {
    f32x4 tm = *(const f32x4*)&tstep[rowbase + (lane >> 4) * 4];
#pragma unroll
    for (int ni = 0; ni < 4; ++ni) {
      i32x4 s = red[0][lane][ni];
#pragma unroll
      for (int u = 1; u < 4; ++u) s += red[u][lane][ni];
      const int col = ni * 16 + (lane & 15);
      const float as = astep[col];
#pragma unroll
      for (int j = 0; j < 4; ++j) {
        int row = rowbase + (lane >> 4) * 4 + j;
        xa[(size_t)row * RNK + col] = (__bf16)((float)s[j] * tm[j] * as);
      }
    }
  }
}

// ==== i8 main GEMM, cross-barrier pipelined ====
// LDS 128 KB: 4 bufs x 32 KB, buf = { A0(8K rows0-127), A1(8K), B0, B1 }.
// Half = 128 rows x 64 i8; row r, 16B-slot s at phys slot s ^ ((r>>1)&3).
// Body(kt): hi(kt-1) [a2-other + B-other regs, both read last body];
// stage(kt+3)->buf[(kt+3)&3]; a2-read(kt); prefetch lo+B(kt+1)->other set;
// lo(kt) [reg-ready]; lgkmcnt(0) [drain a2(kt)+prefetch for cross-wave WAR,
// issued >=1 MFMA-cluster earlier]; vmcnt(4); barrier.
// All 32 MFMAs issued per phase are register-ready; every ds_read gets a
// full phase of slack before its consumer (next body's MFMA clusters).
__global__ __launch_bounds__(512, 1) void gemm_i8_kernel(const signed char* __restrict__ Xi8,
                                                         const signed char* __restrict__ Wi8,
                                                         const float* __restrict__ scale,
                                                         const float* __restrict__ tstep,
                                                         const __bf16* __restrict__ xa,
                                                         const __bf16* __restrict__ Blt,
                                                         float* __restrict__ out) {
  extern __shared__ char smem[];
  const int tid = threadIdx.x;
  const int lane = tid & 63;
  const int w = tid >> 6;
  const int wr = w >> 2;
  const int wc = w & 3;

  const int swz = (blockIdx.x & 7) * 64 + (blockIdx.x >> 3);
  const int bx = swz & 15;
  const int by = swz >> 4;
  const size_t bm = (size_t)by * 256, bn = (size_t)bx * 256;

  const int rc = ((lane >> 4) ^ ((lane >> 1) & 3)) << 4;
  const int srow = tid >> 2;
  const int scol = ((tid & 3) ^ ((tid >> 3) & 3)) << 4;

  auto SH = [&](const signed char* g, size_t r0, int srct, int ldsoff) {
    gload_lds16(g + (r0 + srow) * (size_t)4096 + srct * 64 + scol,
                smem + ldsoff + tid * 16);
  };
  auto stage = [&](int srct, int buf) {
    int b = buf * 32768;
    SH(Xi8, bm, srct, b); SH(Xi8, bm + 128, srct, b + 8192);
    SH(Wi8, bn, srct, b + 16384); SH(Wi8, bn + 128, srct, b + 24576);
  };

  const int aoffw = wr * 8192 + (lane & 15) * 64 + rc;
  const int boffw = 16384 + (wc >> 1) * 8192 + (wc & 1) * 4096 + (lane & 15) * 64 + rc;

  i32x4 aP[4], bP[4], aQ[4], bQ[4], a2P[4], a2Q[4];
  i32x4 acc[8][4] = {};

  // prologue: tiles 0,1,2 staged; vmcnt(4) -> tiles 0,1 landed; preload tile0
  stage(0, 0); stage(1, 1); stage(2, 2);
  asm volatile("s_waitcnt vmcnt(4)" ::: "memory");
  __builtin_amdgcn_s_barrier();
#pragma unroll
  for (int mi = 0; mi < 4; ++mi) aP[mi] = *(const i32x4*)(smem + aoffw + mi * 1024);
#pragma unroll
  for (int ni = 0; ni < 4; ++ni) bP[ni] = *(const i32x4*)(smem + boffw + ni * 1024);

  // body kt: AY/BY = tile-kt frags (cur), AX/BX = other set (holds kt-1 at
  // entry; overwritten with kt+1), a2Y = written (tile kt hi-rows), a2X =
  // consumed (tile kt-1 hi-rows).
  auto body = [&](int kt, i32x4 (&AY)[4], i32x4 (&BY)[4],
                  i32x4 (&AX)[4], i32x4 (&BX)[4],
                  i32x4 (&a2Y)[4], i32x4 (&a2X)[4], bool doHi) {
    if (doHi) {
#pragma unroll
      for (int mi = 0; mi < 4; ++mi)
#pragma unroll
        for (int ni = 0; ni < 4; ++ni)
          acc[4 + mi][ni] = __builtin_amdgcn_mfma_i32_16x16x64_i8(a2X[mi], BX[ni], acc[4 + mi][ni], 0, 0, 0);
    }
    const int st = (kt + 3 < NT) ? kt + 3 : NT - 1;   // clamped dummy keeps vmcnt uniform
    stage(st, (kt + 3) & 3);
    const int ab = (kt & 3) * 32768 + aoffw;
#pragma unroll
    for (int mi = 0; mi < 4; ++mi)
      a2Y[mi] = *(const i32x4*)(smem + ab + 4096 + mi * 1024);
    if (kt + 1 < NT) {
      const int nb = ((kt + 1) & 3) * 32768;
#pragma unroll
      for (int mi = 0; mi < 4; ++mi) AX[mi] = *(const i32x4*)(smem + nb + aoffw + mi * 1024);
#pragma unroll
      for (int ni = 0; ni < 4; ++ni) BX[ni] = *(const i32x4*)(smem + nb + boffw + ni * 1024);
    }
#pragma unroll
    for (int mi = 0; mi < 4; ++mi)
#pragma unroll
      for (int ni = 0; ni < 4; ++ni)
        acc[mi][ni] = __builtin_amdgcn_mfma_i32_16x16x64_i8(AY[mi], BY[ni], acc[mi][ni], 0, 0, 0);
    asm volatile("s_waitcnt lgkmcnt(0)" ::: "memory");   // cross-wave WAR: a2Y/prefetch drained
    __builtin_amdgcn_sched_barrier(0);
    asm volatile("s_waitcnt vmcnt(4)" ::: "memory");
    __builtin_amdgcn_s_barrier();
  };

  body(0, aP, bP, aQ, bQ, a2P, a2Q, false);
  for (int kt = 1; kt < NT - 1; kt += 2) {
    body(kt, aQ, bQ, aP, bP, a2Q, a2P, true);
    body(kt + 1, aP, bP, aQ, bQ, a2P, a2Q, true);
  }
  body(NT - 1, aQ, bQ, aP, bP, a2Q, a2P, true);
  // final hi(NT-1): a2 of 63 in a2Q, B of 63 in bQ (prefetch was skipped)
#pragma unroll
  for (int mi = 0; mi < 4; ++mi)
#pragma unroll
    for (int ni = 0; ni < 4; ++ni)
      acc[4 + mi][ni] = __builtin_amdgcn_mfma_i32_16x16x64_i8(a2Q[mi], bQ[ni], acc[4 + mi][ni], 0, 0, 0);

  // ---- epilogue: drain in-flight dummy stages BEFORE reusing LDS ----
  asm volatile("s_waitcnt vmcnt(0)" ::: "memory");
  __builtin_amdgcn_s_barrier();

  const int sl_row = lane >> 3;
  const int sl_col = ((lane & 7) ^ (lane >> 3)) << 4;
  auto SBF = [&](const __bf16* g, size_t r0, int ldsoff) {
    char* d0 = smem + ldsoff + w * 2048 + lane * 16;
#pragma unroll
    for (int s = 0; s < 2; ++s) {
      const int rl = (w * 2 + s) * 8 + sl_row;
      gload_lds16((const char*)g + (r0 + rl) * 128 + sl_col, d0 + s * 1024);
    }
  };
  SBF(xa, bm, 0); SBF(xa, bm + 128, 16384);
  SBF(Blt, bn, 32768); SBF(Blt, bn + 128, 49152);

  float sc[4];
#pragma unroll
  for (int ni = 0; ni < 4; ++ni)
    sc[ni] = scale[bn + wc * 64 + ni * 16 + (lane & 15)];
  f32x4 tm[8];
#pragma unroll
  for (int mi = 0; mi < 8; ++mi)
    tm[mi] = *(const f32x4*)&tstep[bm + wr * 128 + mi * 16 + (lane >> 4) * 4];

  asm volatile("s_waitcnt vmcnt(0)" ::: "memory");
  __builtin_amdgcn_s_barrier();

  const int cx0 = ((lane >> 4) << 4) ^ ((lane & 7) << 4);
  const int cx1 = (64 | ((lane >> 4) << 4)) ^ ((lane & 7) << 4);
  const int abE = wr * 16384 + (lane & 15) * 128;
  const int bbE = 32768 + (wc >> 1) * 16384 + ((wc & 1) * 64 + (lane & 15)) * 128;

  bf16x8 bl0[4], bl1[4];
#pragma unroll
  for (int ni = 0; ni < 4; ++ni) {
    bl0[ni] = *(const bf16x8*)(smem + bbE + ni * 2048 + cx0);
    bl1[ni] = *(const bf16x8*)(smem + bbE + ni * 2048 + cx1);
  }
#pragma unroll
  for (int mi = 0; mi < 8; ++mi) {
    bf16x8 ax0 = *(const bf16x8*)(smem + abE + mi * 2048 + cx0);
    bf16x8 ax1 = *(const bf16x8*)(smem + abE + mi * 2048 + cx1);
    const size_t row = bm + wr * 128 + mi * 16 + (lane >> 4) * 4;
#pragma unroll
    for (int ni = 0; ni < 4; ++ni) {
      f32x4 l = {0.f, 0.f, 0.f, 0.f};
      l = __builtin_amdgcn_mfma_f32_16x16x32_bf16(ax0, bl0[ni], l, 0, 0, 0);
      l = __builtin_amdgcn_mfma_f32_16x16x32_bf16(ax1, bl1[ni], l, 0, 0, 0);
      const size_t col = bn + wc * 64 + ni * 16 + (lane & 15);
#pragma unroll
      for (int j = 0; j < 4; ++j)
        out[(row + j) * DOUT + col] = (float)acc[mi][ni][j] * (sc[ni] * tm[mi][j]) + l[j];
    }
  }
}

extern "C" void kernel_launch(void* const* d_in, const int* in_sizes, int n_in,
                              void* d_out, int out_size, void* d_ws, size_t ws_size,
                              hipStream_t stream) {
  const float* x = (const float*)d_in[0];
  const int* qw = (const int*)d_in[1];
  const float* scale = (const float*)d_in[2];
  const float* lA = (const float*)d_in[3];
  const float* lB = (const float*)d_in[4];
  float* out = (float*)d_out;

  char* ws = (char*)d_ws;
  signed char* Xi8 = (signed char*)ws;                              // 33.6 MB
  signed char* Wi8 = (signed char*)(ws + 33554432);                 // 16.8 MB
  __bf16* xa    = (__bf16*)(ws + 50331648);                         // 1.05 MB
  signed char* Ai8 = (signed char*)(ws + 51380224);                 // 0.26 MB
  __bf16* Blt   = (__bf16*)(ws + 51904512);                         // 0.52 MB
  float* tstep  = (float*)(ws + 52428800);                          // 32 KB
  float* astep  = (float*)(ws + 52461568);                          // 256 B

  hipFuncSetAttribute((const void*)gemm_i8_kernel,
                      hipFuncAttributeMaxDynamicSharedMemorySize, 131072);

  prep_kernel<<<24896, 256, 0, stream>>>(x, qw, lA, lB, Xi8, tstep, Wi8, Ai8, astep, Blt);
  lora_xa_kernel<<<MTOT / 16, 256, 0, stream>>>(Xi8, tstep, Ai8, astep, xa);
  gemm_i8_kernel<<<(MTOT / 256) * (DOUT / 256), 512, 131072, stream>>>(
      Xi8, Wi8, scale, tstep, xa, Blt, out);
}